// Round 1
// baseline (128.437 us; speedup 1.0000x reference)
//
#include <hip/hip_runtime.h>
#include <math.h>

// x: [B, C, T, F] float32.
// out[b,k,f] = max_{j,t} (x[b,j,t,f] + x[b,k,t,f])
//            = max_t ( x[b,k,t,f] + M[b,t,f] ),  M = max_j x[b,j,t,f]
// (exact: fl(a+b) is monotone in b, so rounded-add commutes with max)
//
// Two pure-streaming, barrier-free passes:
//   Pass 1 (cmax_kernel): M_part[cc][b][t][f] = max over 80-channel chunk cc.
//     256 blocks x 256 threads; each wave reads 1 KB contiguous per channel
//     iteration; writes 1 MB of partials to workspace.
//   Pass 2 (pair_kernel): one block per (b,k). Streams the 64 KB row
//     x[b,k,:,:] (wave-contiguous), folds the two M-parts on the fly
//     (1 MB total -> L2-hot across the 159 k-blocks per b), then
//     shuffle+LDS reduces over t. No inter-phase barriers anywhere.
#define B_DIM 8
#define C_DIM 160
#define T_DIM 512
#define F_DIM 32
#define F4 8               // float4 per (b,c,t) row
#define C1 159             // output channels k = 0..C-2
#define CSPLIT 2           // channel chunks in pass 1
#define CCH (C_DIM / CSPLIT)  // 80 channels per chunk
#define TBLK 32            // t per block in pass 1
#define NTB (T_DIM / TBLK) // 16

__device__ __forceinline__ float4 fmax4(float4 a, float4 b) {
    return make_float4(fmaxf(a.x, b.x), fmaxf(a.y, b.y),
                       fmaxf(a.z, b.z), fmaxf(a.w, b.w));
}
__device__ __forceinline__ float4 fadd4(float4 a, float4 b) {
    return make_float4(a.x + b.x, a.y + b.y, a.z + b.z, a.w + b.w);
}
__device__ __forceinline__ float4 shfl_xor4(float4 v, int m) {
    return make_float4(__shfl_xor(v.x, m), __shfl_xor(v.y, m),
                       __shfl_xor(v.z, m), __shfl_xor(v.w, m));
}
#define NEG_INF4 make_float4(-INFINITY, -INFINITY, -INFINITY, -INFINITY)

// Grid: CSPLIT*B*NTB = 256 blocks of 256.
// mpart layout: [cc][b][t][f4] in float4 units.
__global__ __launch_bounds__(256)
void cmax_kernel(const float* __restrict__ x, float* __restrict__ mpart) {
    const int bi = blockIdx.x;
    const int tb = bi & (NTB - 1);
    const int b  = (bi >> 4) & (B_DIM - 1);
    const int cc = bi >> 7;
    const int tid = threadIdx.x;
    const int f4 = tid & 7;
    const int t = tb * TBLK + (tid >> 3);   // wave: 8 t x 8 f4 = 1 KB contiguous

    const float4* __restrict__ x4 =
        (const float4*)x + ((b * C_DIM + cc * CCH) * T_DIM + t) * F4 + f4;

    float4 acc = NEG_INF4;
    #pragma unroll 8
    for (int ci = 0; ci < CCH; ++ci)
        acc = fmax4(acc, x4[ci * (T_DIM * F4)]);   // stride 64 KB, coalesced

    ((float4*)mpart)[((cc * B_DIM + b) * T_DIM + t) * F4 + f4] = acc;
}

// Grid: B*C1 = 1272 blocks of 256. Each block owns one (b,k).
__global__ __launch_bounds__(256)
void pair_kernel(const float* __restrict__ x, const float* __restrict__ mpart,
                 float* __restrict__ out) {
    const int bi = blockIdx.x;
    const int b = bi / C1;
    const int k = bi - b * C1;
    const int tid = threadIdx.x;
    const int f4 = tid & 7;
    const int tsub = tid >> 3;              // 0..31

    const float4* __restrict__ xk =
        (const float4*)x + (b * C_DIM + k) * (T_DIM * F4);
    const float4* __restrict__ m0 =
        (const float4*)mpart + b * (T_DIM * F4);
    const float4* __restrict__ m1 = m0 + B_DIM * (T_DIM * F4);

    float4 acc = NEG_INF4;
    #pragma unroll 4
    for (int it = 0; it < T_DIM / 32; ++it) {   // 16 iters, 4 KB/block/iter
        const int idx = (it * 32 + tsub) * F4 + f4;
        const float4 m = fmax4(m0[idx], m1[idx]);   // L2-hot (1 MB total)
        acc = fmax4(acc, fadd4(xk[idx], m));
    }

    // reduce over tsub: bits 3,4,5 within the wave, then 4 waves via LDS
    acc = fmax4(acc, shfl_xor4(acc, 8));
    acc = fmax4(acc, shfl_xor4(acc, 16));
    acc = fmax4(acc, shfl_xor4(acc, 32));

    __shared__ float4 red[4][8];
    const int wave = tid >> 6;
    if ((tid & 63) < 8) red[wave][f4] = acc;
    __syncthreads();
    if (tid < 8) {
        const float4 r = fmax4(fmax4(red[0][tid], red[1][tid]),
                               fmax4(red[2][tid], red[3][tid]));
        ((float4*)out)[(b * C1 + k) * F4 + tid] = r;
    }
}

extern "C" void kernel_launch(void* const* d_in, const int* in_sizes, int n_in,
                              void* d_out, int out_size, void* d_ws, size_t ws_size,
                              hipStream_t stream) {
    const float* x = (const float*)d_in[0];
    float* out = (float*)d_out;
    float* mpart = (float*)d_ws;  // CSPLIT*B*T*F floats = 1 MB scratch

    cmax_kernel<<<CSPLIT * B_DIM * NTB, 256, 0, stream>>>(x, mpart);  // 256 blocks
    pair_kernel<<<B_DIM * C1, 256, 0, stream>>>(x, mpart, out);       // 1272 blocks
}

// Round 2
// 122.724 us; speedup vs baseline: 1.0465x; 1.0465x over previous
//
#include <hip/hip_runtime.h>
#include <math.h>

// x: [B, C, T, F] float32.
// out[b,k,f] = max_{j,t} (x[b,j,t,f] + x[b,k,t,f])
//            = max_t ( x[b,k,t,f] + M[b,t,f] ),  M = max_j x[b,j,t,f]  (exact:
//              fl(a+b) is monotone in b, so rounded-add commutes with max)
//
// Single HBM pass: block owns (b, 8-t chunk); loops 4 sub-chunks of 2 t.
// Each sub-chunk (160c x 2t x 32f = 40 KB) is staged to LDS while the
// channel-max M_sub is computed in-register (shfl reduce). Phase B then reads
// x[k] from LDS (not L2/L3) and accumulates into registers. Partials
// [B,C1,NT,F] are folded by a tiny combine kernel.
//
// v2: software-pipelined staging — sub-chunk s+1's 10 global loads are issued
// into registers right after sub-chunk s's LDS writes, BEFORE the barriers,
// so HBM latency hides under Phase B + both __syncthreads (at 2 blocks/CU
// there is little cross-block overlap to hide it otherwise).
#define B_DIM 8
#define C_DIM 160
#define T_DIM 512
#define F_DIM 32
#define F4 8              // float4 per (b,c,t) row
#define C1 159            // output channels k = 0..C-2
#define TCH 8             // t per chunk (per block)
#define NT (T_DIM / TCH)  // 64 chunks per b
#define NSUB 4            // sub-chunks per chunk (2 t each)
#define KPAD 17           // padded k-row stride in float4 (16 data + 1 pad)

__device__ __forceinline__ float4 fmax4(float4 a, float4 b) {
    return make_float4(fmaxf(a.x, b.x), fmaxf(a.y, b.y),
                       fmaxf(a.z, b.z), fmaxf(a.w, b.w));
}
__device__ __forceinline__ float4 fadd4(float4 a, float4 b) {
    return make_float4(a.x + b.x, a.y + b.y, a.z + b.z, a.w + b.w);
}
__device__ __forceinline__ float4 shfl_xor4(float4 v, int m) {
    return make_float4(__shfl_xor(v.x, m), __shfl_xor(v.y, m),
                       __shfl_xor(v.z, m), __shfl_xor(v.w, m));
}
#define NEG_INF4 make_float4(-INFINITY, -INFINITY, -INFINITY, -INFINITY)

// Grid: B*NT blocks of 256. partial layout: [b][k][tc][f4] (float4 units).
__global__ __launch_bounds__(256)
void fused_kernel(const float* __restrict__ x, float* __restrict__ partial) {
    const int blk = blockIdx.x;
    const int b = blk >> 6;                 // / NT
    const int tc = blk & (NT - 1);
    const int t_base = tc * TCH;
    const int tid = threadIdx.x;
    const int f4 = tid & 7;
    const int eid = tid & 15;               // (tl<<3)|f4 within a 2-t sub-chunk
    const int cg = tid >> 4;                // 0..15 channel group
    const int wave = tid >> 6;              // 0..3

    const float4* __restrict__ x4 = (const float4*)x;
    float4* __restrict__ p4 = (float4*)partial;

    __shared__ float4 Xlds[C_DIM * KPAD];   // 160 x 17 float4 = 42.5 KB
    __shared__ float4 redw[4 * 16];         // per-wave channel-max partials

    const int kg = tid >> 3;                // 0..31 (Phase B)
    float4 accK[5];
    #pragma unroll
    for (int ki = 0; ki < 5; ++ki) accK[ki] = NEG_INF4;

    // per-thread base for sub-chunk staging loads; advances by 16 float4 per s
    // (2 t * 8 f4). addr(s=0,i): ((b*C + cg+16i)*T + t_base)*F4 + eid
    const float4* xs = x4 + ((b * C_DIM + cg) * T_DIM + t_base) * F4 + eid;

    // prologue: stage sub-chunk 0 into registers
    float4 vbuf[10];
    #pragma unroll
    for (int i = 0; i < 10; ++i)
        vbuf[i] = xs[i * (16 * T_DIM * F4)];

    for (int s = 0; s < NSUB; ++s) {
        // ---- Phase A: registers -> LDS + in-register channel max ----
        float4 macc = NEG_INF4;
        #pragma unroll
        for (int i = 0; i < 10; ++i) {
            const int c = cg + 16 * i;
            Xlds[c * KPAD + eid] = vbuf[i];
            macc = fmax4(macc, vbuf[i]);
        }

        // ---- prefetch sub-chunk s+1 (completes during reduce + Phase B) ----
        if (s + 1 < NSUB) {
            const float4* xn = xs + (s + 1) * (2 * F4);   // +2 t
            #pragma unroll
            for (int i = 0; i < 10; ++i)
                vbuf[i] = xn[i * (16 * T_DIM * F4)];
        }

        // in-wave reduce over the 4 cg groups per wave (bits 4,5 of lane)
        macc = fmax4(macc, shfl_xor4(macc, 16));
        macc = fmax4(macc, shfl_xor4(macc, 32));
        if ((tid & 63) < 16) redw[wave * 16 + eid] = macc;
        __syncthreads();

        // every thread folds the 4 per-wave partials for its two eids
        float4 m0 = fmax4(fmax4(redw[f4],      redw[16 + f4]),
                          fmax4(redw[32 + f4], redw[48 + f4]));
        float4 m1 = fmax4(fmax4(redw[8 + f4],      redw[16 + 8 + f4]),
                          fmax4(redw[32 + 8 + f4], redw[48 + 8 + f4]));

        // ---- Phase B: accK[ki] = max(accK, x[k, t0+tl, f4] + M[tl]) ----
        #pragma unroll
        for (int ki = 0; ki < 5; ++ki) {
            const int k = kg + 32 * ki;
            if (k < C1) {
                accK[ki] = fmax4(accK[ki],
                                 fadd4(Xlds[k * KPAD + f4], m0));
                accK[ki] = fmax4(accK[ki],
                                 fadd4(Xlds[k * KPAD + 8 + f4], m1));
            }
        }
        __syncthreads();   // before next sub-chunk overwrites Xlds
    }

    #pragma unroll
    for (int ki = 0; ki < 5; ++ki) {
        const int k = kg + 32 * ki;
        if (k < C1)
            p4[((b * C1 + k) * NT + tc) * F4 + f4] = accK[ki];
    }
}

// Grid: B*C1 waves. out[b,k,f] = max_tc partial[b,k,tc,f].
__global__ __launch_bounds__(64)
void combine_kernel(const float* __restrict__ partial, float* __restrict__ out) {
    const int bk = blockIdx.x;              // b*C1 + k
    const int lane = threadIdx.x;
    const float4* __restrict__ p = (const float4*)partial + bk * (NT * F4);

    float4 acc = NEG_INF4;
    #pragma unroll
    for (int j = 0; j < (NT * F4) / 64; ++j)    // 8 iters, fully coalesced
        acc = fmax4(acc, p[j * 64 + lane]);

    acc = fmax4(acc, shfl_xor4(acc, 8));
    acc = fmax4(acc, shfl_xor4(acc, 16));
    acc = fmax4(acc, shfl_xor4(acc, 32));
    if (lane < 8)
        ((float4*)out)[bk * F4 + lane] = acc;   // flat bk*F + lane*4
}

extern "C" void kernel_launch(void* const* d_in, const int* in_sizes, int n_in,
                              void* d_out, int out_size, void* d_ws, size_t ws_size,
                              hipStream_t stream) {
    const float* x = (const float*)d_in[0];
    float* out = (float*)d_out;
    float* partial = (float*)d_ws;  // B*C1*NT*F floats = 10.4 MB scratch

    fused_kernel<<<B_DIM * NT, 256, 0, stream>>>(x, partial);     // 512 blocks
    combine_kernel<<<B_DIM * C1, 64, 0, stream>>>(partial, out);  // 1272 waves
}